// Round 9
// baseline (202.669 us; speedup 1.0000x reference)
//
#include <hip/hip_runtime.h>
#include <math.h>

#define B_ 4
#define S_ 1024
#define D_ 1024
#define H_ 16
#define DK_ 64

typedef short bf16x8 __attribute__((ext_vector_type(8)));
typedef float f32x4 __attribute__((ext_vector_type(4)));

__device__ __forceinline__ unsigned short f2bf(float f) {
    unsigned int u = __float_as_uint(f);
    u = (u + 0x7FFFu + ((u >> 16) & 1u)) >> 16;  // RNE
    return (unsigned short)u;
}

__device__ __forceinline__ float exp2_fast(float x) {
#if __has_builtin(__builtin_amdgcn_exp2f)
    return __builtin_amdgcn_exp2f(x);
#else
    return exp2f(x);
#endif
}

__device__ __forceinline__ unsigned pack_bf16(float a, float b) {
#if __has_builtin(__builtin_amdgcn_cvt_pk_bf16_f32)
    auto v = __builtin_amdgcn_cvt_pk_bf16_f32(a, b);
    return __builtin_bit_cast(unsigned int, v);
#else
    return (unsigned)f2bf(a) | ((unsigned)f2bf(b) << 16);
#endif
}

// lane^1 exchange via DPP quad_perm [1,0,3,2] — VALU, not LDS pipe
__device__ __forceinline__ float dpp_xor1(float x) {
#if __has_builtin(__builtin_amdgcn_update_dpp)
    int i = __builtin_bit_cast(int, x);
    int r = __builtin_amdgcn_update_dpp(0, i, 0xB1, 0xF, 0xF, true);
    return __builtin_bit_cast(float, r);
#else
    return __shfl_xor(x, 1);
#endif
}

// async 16B/lane global -> LDS (lands at lds_base + lane*16)
__device__ __forceinline__ void gl2lds16(const void* g, void* l) {
    typedef unsigned int u32;
    auto gp = (const __attribute__((address_space(1))) u32*)(unsigned long long)g;
    auto lp = (__attribute__((address_space(3))) u32*)(unsigned int)(unsigned long long)l;
    __builtin_amdgcn_global_load_lds(gp, lp, 16, 0, 0);
}

#define LOG2E 1.44269504f
#define BIAS_OFF 20.0f

// ---------------------------------------------------------------------------
// fused conversion kernel: blocks [0,4096) convert x -> bf16;
// blocks [4096,8192) transpose+convert the 4 weight matrices -> Wts
// ---------------------------------------------------------------------------
__global__ __launch_bounds__(256) void conv_all(
    const float* __restrict__ x,
    const float* __restrict__ W0, const float* __restrict__ W1,
    const float* __restrict__ W2, const float* __restrict__ W3,
    unsigned short* __restrict__ xb, unsigned short* __restrict__ Wts)
{
    __shared__ float T[32][33];
    const int t = threadIdx.x;
    const int bid = blockIdx.x;

    if (bid < 4096) {
        int i = (bid * 256 + t) * 4;
        float4 v = *(const float4*)&x[i];
        ushort4 o;
        o.x = f2bf(v.x); o.y = f2bf(v.y); o.z = f2bf(v.z); o.w = f2bf(v.w);
        *(ushort4*)&xb[i] = o;
        return;
    }
    int tile = bid - 4096;
    const int mat = tile >> 10;
    tile &= 1023;
    const float* W = (mat == 0) ? W0 : (mat == 1) ? W1 : (mat == 2) ? W2 : W3;
    unsigned short* Wt = Wts + (size_t)mat * 1048576;
    const int k0 = (tile >> 5) * 32, n0 = (tile & 31) * 32;
    {
        int r = t >> 3, c4 = (t & 7) * 4;
        float4 v = *(const float4*)&W[(size_t)(k0 + r) * D_ + n0 + c4];
        T[r][c4 + 0] = v.x; T[r][c4 + 1] = v.y; T[r][c4 + 2] = v.z; T[r][c4 + 3] = v.w;
    }
    __syncthreads();
    {
        int rn = t >> 3, c4 = (t & 7) * 4;
        ushort4 o;
        o.x = f2bf(T[c4 + 0][rn]); o.y = f2bf(T[c4 + 1][rn]);
        o.z = f2bf(T[c4 + 2][rn]); o.w = f2bf(T[c4 + 3][rn]);
        *(ushort4*)&Wt[(size_t)(n0 + rn) * D_ + k0 + c4] = o;
    }
}

// ---------------------------------------------------------------------------
// bf16 MFMA GEMM 128x128, BK=32, async staging. Flat grid 768, XCD-swizzled:
// bid%8 == by%8, so all 24 blocks sharing an x row-tile live on one XCD.
// ---------------------------------------------------------------------------
__global__ __launch_bounds__(256) void gemm_qkv(
    const unsigned short* __restrict__ xb,
    const unsigned short* __restrict__ Wts,
    unsigned short* __restrict__ Qb, unsigned short* __restrict__ Kb,
    unsigned short* __restrict__ Vtb)
{
    const int bid = blockIdx.x;
    const int by = bid & 31;          // x row-tile: XCD residue = by%8
    const int t_ = bid >> 5;          // 0..23
    const int z = t_ >> 3;            // 0..2 (Wq/Wk/Wv)
    const int bx = t_ & 7;            // W col-tile
    const unsigned short* Bt = Wts + (size_t)z * 1048576;

    __shared__ __align__(16) unsigned short Ast[128][32];
    __shared__ __align__(16) unsigned short Bst[128][32];

    const int tid = threadIdx.x;
    const int wave = tid >> 6, lane = tid & 63;
    const int quad = lane >> 4, l16 = lane & 15;
    const int wm = (wave & 1) * 64, wn = (wave >> 1) * 64;
    const int row0 = by * 128, col0 = bx * 128;
    const int lr = lane >> 2, lc = (lane & 3) * 8;

    f32x4 acc[4][4];
#pragma unroll
    for (int i = 0; i < 4; i++)
#pragma unroll
        for (int j = 0; j < 4; j++) acc[i][j] = 0;

    for (int k0 = 0; k0 < D_; k0 += 32) {
        __syncthreads();
#pragma unroll
        for (int c = 0; c < 2; c++) {
            int m = wave * 32 + c * 16;
            gl2lds16(&xb[(size_t)(row0 + m + lr) * D_ + k0 + lc], &Ast[m][0]);
            gl2lds16(&Bt[(size_t)(col0 + m + lr) * D_ + k0 + lc], &Bst[m][0]);
        }
        __syncthreads();

        bf16x8 af[4], bfr[4];
#pragma unroll
        for (int mt = 0; mt < 4; mt++)
            af[mt] = *(const bf16x8*)&Ast[wm + mt * 16 + l16][quad * 8];
#pragma unroll
        for (int nt = 0; nt < 4; nt++)
            bfr[nt] = *(const bf16x8*)&Bst[wn + nt * 16 + l16][quad * 8];
#pragma unroll
        for (int mt = 0; mt < 4; mt++)
#pragma unroll
            for (int nt = 0; nt < 4; nt++)
                acc[mt][nt] = __builtin_amdgcn_mfma_f32_16x16x32_bf16(
                    af[mt], bfr[nt], acc[mt][nt], 0, 0, 0);
    }

    const float scale = (z == 0) ? LOG2E : 1.0f;
#pragma unroll
    for (int mt = 0; mt < 4; mt++)
#pragma unroll
        for (int nt = 0; nt < 4; nt++)
#pragma unroll
            for (int reg = 0; reg < 4; reg++) {
                int row = row0 + wm + mt * 16 + quad * 4 + reg;
                int col = col0 + wn + nt * 16 + l16;
                int b = row >> 10, s = row & 1023;
                int h = col >> 6, dk = col & 63;
                unsigned short v = f2bf(acc[mt][nt][reg] * scale);
                if (z == 0)      Qb[(((size_t)(b * H_ + h)) * S_ + s) * DK_ + dk] = v;
                else if (z == 1) Kb[(((size_t)(b * H_ + h)) * S_ + s) * DK_ + dk] = v;
                else             Vtb[(((size_t)(b * H_ + h)) * DK_ + dk) * S_ + s] = v;
            }
}

// ---------------------------------------------------------------------------
// Output GEMM: 64x128 tile, BK=32. Flat grid 512, XCD-swizzled (bid%8==by%8).
// ---------------------------------------------------------------------------
__global__ __launch_bounds__(256) void gemm_out(
    const unsigned short* __restrict__ Ab,
    const unsigned short* __restrict__ Bt,
    float* __restrict__ out)
{
    const int bid = blockIdx.x;
    const int by = bid & 63;          // A row-tile: XCD residue = by%8
    const int bx = bid >> 6;          // 0..7

    __shared__ __align__(16) unsigned short Ast[64][32];
    __shared__ __align__(16) unsigned short Bst[128][32];

    const int tid = threadIdx.x;
    const int wave = tid >> 6, lane = tid & 63;
    const int quad = lane >> 4, l16 = lane & 15;
    const int wm = (wave & 1) * 32, wn = (wave >> 1) * 64;
    const int row0 = by * 64, col0 = bx * 128;
    const int lr = lane >> 2, lc = (lane & 3) * 8;

    f32x4 acc[2][4];
#pragma unroll
    for (int i = 0; i < 2; i++)
#pragma unroll
        for (int j = 0; j < 4; j++) acc[i][j] = 0;

    for (int k0 = 0; k0 < D_; k0 += 32) {
        __syncthreads();
        gl2lds16(&Ab[(size_t)(row0 + wave * 16 + lr) * D_ + k0 + lc],
                 &Ast[wave * 16][0]);
#pragma unroll
        for (int c = 0; c < 2; c++) {
            int m = (wave * 2 + c) * 16;
            gl2lds16(&Bt[(size_t)(col0 + m + lr) * D_ + k0 + lc], &Bst[m][0]);
        }
        __syncthreads();

        bf16x8 af[2], bfr[4];
#pragma unroll
        for (int mt = 0; mt < 2; mt++)
            af[mt] = *(const bf16x8*)&Ast[wm + mt * 16 + l16][quad * 8];
#pragma unroll
        for (int nt = 0; nt < 4; nt++)
            bfr[nt] = *(const bf16x8*)&Bst[wn + nt * 16 + l16][quad * 8];
#pragma unroll
        for (int mt = 0; mt < 2; mt++)
#pragma unroll
            for (int nt = 0; nt < 4; nt++)
                acc[mt][nt] = __builtin_amdgcn_mfma_f32_16x16x32_bf16(
                    af[mt], bfr[nt], acc[mt][nt], 0, 0, 0);
    }

#pragma unroll
    for (int mt = 0; mt < 2; mt++)
#pragma unroll
        for (int nt = 0; nt < 4; nt++)
#pragma unroll
            for (int reg = 0; reg < 4; reg++) {
                int row = row0 + wm + mt * 16 + quad * 4 + reg;
                int col = col0 + wn + nt * 16 + l16;
                out[(size_t)row * D_ + col] = acc[mt][nt][reg];
            }
}

// ---------------------------------------------------------------------------
// MFMA flash attention. Round-7 structure (q-tile 128, 2 subs/wave) with
// K-chunk 256: 4 kt iterations, half the barriers, same 2 blocks/CU
// (LDS 77 KB; 2x77 < 160). XCD swizzle: bid%8 == bh%8 keeps each (b,h)'s
// K/V on one XCD's L2.
// ---------------------------------------------------------------------------
__global__ __launch_bounds__(256) void attn_mfma(
    const unsigned short* __restrict__ Qb, const unsigned short* __restrict__ Kb,
    const unsigned short* __restrict__ Vtb, const float* __restrict__ rel_emb,
    unsigned short* __restrict__ CTXb)
{
    __shared__ __align__(16) unsigned short Ks[2][256][32];   // [d-half][kc][d32]
    __shared__ __align__(16) unsigned short Vts[8][64][32];   // [kc-eighth][d][kc32]
    __shared__ __align__(16) unsigned short Pw[4][16][40];    // [wave][q][kc32 pad40]
    __shared__ float bias_tab[2047];

    const int bid = blockIdx.x;
    const int bh = bid & 63;          // (b,h): XCD residue = bh%8
    const int b = bh >> 4, h = bh & 15;
    const int q0 = (bid >> 6) * 128;
    const int tid = threadIdx.x;
    const int wave = tid >> 6, lane = tid & 63;
    const int quad = lane >> 4, l16 = lane & 15;
    const int qw = q0 + wave * 32;

    for (int idx = tid; idx < 2047; idx += 256) {
        int rel = idx - 1023;  // k - q
        int n = -rel, ret = 0;
        if (n < 0) { ret = 16; n = -n; }
        int bkt;
        if (n < 8) bkt = ret + n;
        else {
            float t = logf((float)n / 8.0f) / logf(16.0f) * 8.0f;
            int v = 8 + (int)t;
            if (v > 15) v = 15;
            bkt = ret + v;
        }
        bias_tab[idx] = rel_emb[bkt * H_ + h] * LOG2E - BIAS_OFF;
    }

    const size_t hb = (size_t)(b * H_ + h) * (S_ * DK_);
    const unsigned short* Qp = Qb + hb;
    const unsigned short* Kp = Kb + hb;
    const unsigned short* Vp = Vtb + hb;

    bf16x8 qf[2][2];
#pragma unroll
    for (int sub = 0; sub < 2; sub++)
#pragma unroll
        for (int ks = 0; ks < 2; ks++)
            qf[sub][ks] = *(const bf16x8*)
                &Qp[(size_t)(qw + sub * 16 + l16) * DK_ + ks * 32 + quad * 8];

    f32x4 O[2][4];
#pragma unroll
    for (int sub = 0; sub < 2; sub++)
#pragma unroll
        for (int dt = 0; dt < 4; dt++) O[sub][dt] = 0;
    float lsum[2][4] = {{0.f, 0.f, 0.f, 0.f}, {0.f, 0.f, 0.f, 0.f}};

    const int lr = lane >> 2, lc8 = (lane & 3) * 8;
    const int pcol = (l16 & 1) ? (8 + (l16 >> 1)) : (l16 >> 1);
    unsigned* pwp = (unsigned*)&Pw[wave][0][0];   // row stride = 20 dwords

    for (int kt = 0; kt < 4; kt++) {
        const int k0 = kt * 256;
        __syncthreads();
#pragma unroll
        for (int i = 0; i < 8; i++) {
            int idx = wave * 8 + i;   // 0..31
            {   // K chunk: 256 rows x 64 shorts, 2 d-halves of 32
                int s = idx >> 4, rg = idx & 15;
                gl2lds16(&Kp[(size_t)(k0 + rg * 16 + lr) * DK_ + s * 32 + lc8],
                         &Ks[s][rg * 16][0]);
            }
            {   // Vt chunk: 64 rows x 256 shorts, 8 kc-eighths of 32
                int qt = idx >> 2, rg = idx & 3;
                gl2lds16(&Vp[(size_t)(rg * 16 + lr) * S_ + k0 + qt * 32 + lc8],
                         &Vts[qt][rg * 16][0]);
            }
        }
        __syncthreads();

#pragma unroll
        for (int nt2 = 0; nt2 < 8; nt2++) {
            bf16x8 kf[2][2], vf[4];
#pragma unroll
            for (int t = 0; t < 2; t++)
#pragma unroll
                for (int ks = 0; ks < 2; ks++)
                    kf[t][ks] = *(const bf16x8*)
                        &Ks[ks][(2 * nt2 + t) * 16 + l16][quad * 8];
#pragma unroll
            for (int dt = 0; dt < 4; dt++)
                vf[dt] = *(const bf16x8*)&Vts[nt2][dt * 16 + l16][quad * 8];

#pragma unroll
            for (int sub = 0; sub < 2; sub++) {
                const int sb = qw + sub * 16;
                f32x4 sacc[2];
#pragma unroll
                for (int t = 0; t < 2; t++) {
                    int b0 = 1023 + k0 + (2 * nt2 + t) * 16 + l16 - (sb + quad * 4 + 3);
                    float bl[4];
#pragma unroll
                    for (int j = 0; j < 4; j++) bl[j] = bias_tab[b0 + j];
#pragma unroll
                    for (int reg = 0; reg < 4; reg++) sacc[t][reg] = bl[3 - reg];
                }
#pragma unroll
                for (int ks = 0; ks < 2; ks++)
#pragma unroll
                    for (int t = 0; t < 2; t++)
                        sacc[t] = __builtin_amdgcn_mfma_f32_16x16x32_bf16(
                            qf[sub][ks], kf[t][ks], sacc[t], 0, 0, 0);

#pragma unroll
                for (int reg = 0; reg < 4; reg++) {
                    float pa = exp2_fast(sacc[0][reg]);
                    float pb = exp2_fast(sacc[1][reg]);
                    lsum[sub][reg] += pa + pb;
                    float pax = dpp_xor1(pa), pbx = dpp_xor1(pb);
                    unsigned ue = pack_bf16(pa, pax);
                    unsigned uo = pack_bf16(pbx, pb);
                    pwp[(quad * 4 + reg) * 20 + pcol] = (l16 & 1) ? uo : ue;
                }

                bf16x8 pf = *(const bf16x8*)&Pw[wave][l16][quad * 8];
#pragma unroll
                for (int dt = 0; dt < 4; dt++)
                    O[sub][dt] = __builtin_amdgcn_mfma_f32_16x16x32_bf16(
                        pf, vf[dt], O[sub][dt], 0, 0, 0);
            }
        }
    }

#pragma unroll
    for (int sub = 0; sub < 2; sub++)
#pragma unroll
        for (int reg = 0; reg < 4; reg++) {
            float l = lsum[sub][reg];
#pragma unroll
            for (int off = 1; off < 16; off <<= 1)
                l += __shfl_xor(l, off);
            float inv = 1.0f / l;
            int s = qw + sub * 16 + quad * 4 + reg;
#pragma unroll
            for (int dt = 0; dt < 4; dt++) {
                int col = h * DK_ + dt * 16 + l16;
                CTXb[((size_t)(b * S_ + s)) * D_ + col] = f2bf(O[sub][dt][reg] * inv);
            }
        }
}

// ---------------------------------------------------------------------------
extern "C" void kernel_launch(void* const* d_in, const int* in_sizes, int n_in,
                              void* d_out, int out_size, void* d_ws, size_t ws_size,
                              hipStream_t stream) {
    const float* x   = (const float*)d_in[0];
    const float* Wq  = (const float*)d_in[1];
    const float* Wk  = (const float*)d_in[2];
    const float* Wv  = (const float*)d_in[3];
    const float* Wo  = (const float*)d_in[4];
    const float* rel = (const float*)d_in[5];
    float* out = (float*)d_out;

    unsigned short* ws = (unsigned short*)d_ws;
    unsigned short* xb   = ws;                       // 4194304
    unsigned short* Wts  = ws + (size_t)4194304;     // 4x1048576
    unsigned short* Qb   = ws + (size_t)8388608;
    unsigned short* Kb   = ws + (size_t)12582912;
    unsigned short* Vtb  = ws + (size_t)16777216;
    unsigned short* CTXb = ws + (size_t)20971520;

    conv_all<<<8192, 256, 0, stream>>>(x, Wq, Wk, Wv, Wo, xb, Wts);
    gemm_qkv<<<768, 256, 0, stream>>>(xb, Wts, Qb, Kb, Vtb);
    attn_mfma<<<512, 256, 0, stream>>>(Qb, Kb, Vtb, rel, CTXb);
    gemm_out<<<512, 256, 0, stream>>>(CTXb, Wts + (size_t)3 * 1048576, out);
}

// Round 10
// 185.174 us; speedup vs baseline: 1.0945x; 1.0945x over previous
//
#include <hip/hip_runtime.h>
#include <math.h>

#define B_ 4
#define S_ 1024
#define D_ 1024
#define H_ 16
#define DK_ 64

typedef short bf16x8 __attribute__((ext_vector_type(8)));
typedef float f32x4 __attribute__((ext_vector_type(4)));

__device__ __forceinline__ unsigned short f2bf(float f) {
    unsigned int u = __float_as_uint(f);
    u = (u + 0x7FFFu + ((u >> 16) & 1u)) >> 16;  // RNE
    return (unsigned short)u;
}

__device__ __forceinline__ float exp2_fast(float x) {
#if __has_builtin(__builtin_amdgcn_exp2f)
    return __builtin_amdgcn_exp2f(x);
#else
    return exp2f(x);
#endif
}

__device__ __forceinline__ unsigned pack_bf16(float a, float b) {
#if __has_builtin(__builtin_amdgcn_cvt_pk_bf16_f32)
    auto v = __builtin_amdgcn_cvt_pk_bf16_f32(a, b);
    return __builtin_bit_cast(unsigned int, v);
#else
    return (unsigned)f2bf(a) | ((unsigned)f2bf(b) << 16);
#endif
}

// lane^1 exchange via DPP quad_perm [1,0,3,2] — VALU, not LDS pipe
__device__ __forceinline__ float dpp_xor1(float x) {
#if __has_builtin(__builtin_amdgcn_update_dpp)
    int i = __builtin_bit_cast(int, x);
    int r = __builtin_amdgcn_update_dpp(0, i, 0xB1, 0xF, 0xF, true);
    return __builtin_bit_cast(float, r);
#else
    return __shfl_xor(x, 1);
#endif
}

// async 16B/lane global -> LDS (lands at lds_base + lane*16)
__device__ __forceinline__ void gl2lds16(const void* g, void* l) {
    typedef unsigned int u32;
    auto gp = (const __attribute__((address_space(1))) u32*)(unsigned long long)g;
    auto lp = (__attribute__((address_space(3))) u32*)(unsigned int)(unsigned long long)l;
    __builtin_amdgcn_global_load_lds(gp, lp, 16, 0, 0);
}

#define LOG2E 1.44269504f
#define BIAS_OFF 20.0f

// ---------------------------------------------------------------------------
// fused conversion kernel: blocks [0,4096) convert x -> bf16;
// blocks [4096,8192) transpose+convert the 4 weight matrices -> Wts
// ---------------------------------------------------------------------------
__global__ __launch_bounds__(256) void conv_all(
    const float* __restrict__ x,
    const float* __restrict__ W0, const float* __restrict__ W1,
    const float* __restrict__ W2, const float* __restrict__ W3,
    unsigned short* __restrict__ xb, unsigned short* __restrict__ Wts)
{
    __shared__ float T[32][33];
    const int t = threadIdx.x;
    const int bid = blockIdx.x;

    if (bid < 4096) {
        int i = (bid * 256 + t) * 4;
        float4 v = *(const float4*)&x[i];
        ushort4 o;
        o.x = f2bf(v.x); o.y = f2bf(v.y); o.z = f2bf(v.z); o.w = f2bf(v.w);
        *(ushort4*)&xb[i] = o;
        return;
    }
    int tile = bid - 4096;
    const int mat = tile >> 10;
    tile &= 1023;
    const float* W = (mat == 0) ? W0 : (mat == 1) ? W1 : (mat == 2) ? W2 : W3;
    unsigned short* Wt = Wts + (size_t)mat * 1048576;
    const int k0 = (tile >> 5) * 32, n0 = (tile & 31) * 32;
    {
        int r = t >> 3, c4 = (t & 7) * 4;
        float4 v = *(const float4*)&W[(size_t)(k0 + r) * D_ + n0 + c4];
        T[r][c4 + 0] = v.x; T[r][c4 + 1] = v.y; T[r][c4 + 2] = v.z; T[r][c4 + 3] = v.w;
    }
    __syncthreads();
    {
        int rn = t >> 3, c4 = (t & 7) * 4;
        ushort4 o;
        o.x = f2bf(T[c4 + 0][rn]); o.y = f2bf(T[c4 + 1][rn]);
        o.z = f2bf(T[c4 + 2][rn]); o.w = f2bf(T[c4 + 3][rn]);
        *(ushort4*)&Wt[(size_t)(n0 + rn) * D_ + k0 + c4] = o;
    }
}

// ---------------------------------------------------------------------------
// bf16 MFMA GEMM 128x128, BK=32, async staging. Flat grid 768, XCD-swizzled:
// bid%8 == by%8, so all 24 blocks sharing an x row-tile live on one XCD.
// ---------------------------------------------------------------------------
__global__ __launch_bounds__(256) void gemm_qkv(
    const unsigned short* __restrict__ xb,
    const unsigned short* __restrict__ Wts,
    unsigned short* __restrict__ Qb, unsigned short* __restrict__ Kb,
    unsigned short* __restrict__ Vtb)
{
    const int bid = blockIdx.x;
    const int by = bid & 31;          // x row-tile: XCD residue = by%8
    const int t_ = bid >> 5;          // 0..23
    const int z = t_ >> 3;            // 0..2 (Wq/Wk/Wv)
    const int bx = t_ & 7;            // W col-tile
    const unsigned short* Bt = Wts + (size_t)z * 1048576;

    __shared__ __align__(16) unsigned short Ast[128][32];
    __shared__ __align__(16) unsigned short Bst[128][32];

    const int tid = threadIdx.x;
    const int wave = tid >> 6, lane = tid & 63;
    const int quad = lane >> 4, l16 = lane & 15;
    const int wm = (wave & 1) * 64, wn = (wave >> 1) * 64;
    const int row0 = by * 128, col0 = bx * 128;
    const int lr = lane >> 2, lc = (lane & 3) * 8;

    f32x4 acc[4][4];
#pragma unroll
    for (int i = 0; i < 4; i++)
#pragma unroll
        for (int j = 0; j < 4; j++) acc[i][j] = 0;

    for (int k0 = 0; k0 < D_; k0 += 32) {
        __syncthreads();
#pragma unroll
        for (int c = 0; c < 2; c++) {
            int m = wave * 32 + c * 16;
            gl2lds16(&xb[(size_t)(row0 + m + lr) * D_ + k0 + lc], &Ast[m][0]);
            gl2lds16(&Bt[(size_t)(col0 + m + lr) * D_ + k0 + lc], &Bst[m][0]);
        }
        __syncthreads();

        bf16x8 af[4], bfr[4];
#pragma unroll
        for (int mt = 0; mt < 4; mt++)
            af[mt] = *(const bf16x8*)&Ast[wm + mt * 16 + l16][quad * 8];
#pragma unroll
        for (int nt = 0; nt < 4; nt++)
            bfr[nt] = *(const bf16x8*)&Bst[wn + nt * 16 + l16][quad * 8];
#pragma unroll
        for (int mt = 0; mt < 4; mt++)
#pragma unroll
            for (int nt = 0; nt < 4; nt++)
                acc[mt][nt] = __builtin_amdgcn_mfma_f32_16x16x32_bf16(
                    af[mt], bfr[nt], acc[mt][nt], 0, 0, 0);
    }

    const float scale = (z == 0) ? LOG2E : 1.0f;
#pragma unroll
    for (int mt = 0; mt < 4; mt++)
#pragma unroll
        for (int nt = 0; nt < 4; nt++)
#pragma unroll
            for (int reg = 0; reg < 4; reg++) {
                int row = row0 + wm + mt * 16 + quad * 4 + reg;
                int col = col0 + wn + nt * 16 + l16;
                int b = row >> 10, s = row & 1023;
                int h = col >> 6, dk = col & 63;
                unsigned short v = f2bf(acc[mt][nt][reg] * scale);
                if (z == 0)      Qb[(((size_t)(b * H_ + h)) * S_ + s) * DK_ + dk] = v;
                else if (z == 1) Kb[(((size_t)(b * H_ + h)) * S_ + s) * DK_ + dk] = v;
                else             Vtb[(((size_t)(b * H_ + h)) * DK_ + dk) * S_ + s] = v;
            }
}

// ---------------------------------------------------------------------------
// Output GEMM: 64x128 tile, BK=32. Flat grid 512, XCD-swizzled (bid%8==by%8).
// ---------------------------------------------------------------------------
__global__ __launch_bounds__(256) void gemm_out(
    const unsigned short* __restrict__ Ab,
    const unsigned short* __restrict__ Bt,
    float* __restrict__ out)
{
    const int bid = blockIdx.x;
    const int by = bid & 63;          // A row-tile: XCD residue = by%8
    const int bx = bid >> 6;          // 0..7

    __shared__ __align__(16) unsigned short Ast[64][32];
    __shared__ __align__(16) unsigned short Bst[128][32];

    const int tid = threadIdx.x;
    const int wave = tid >> 6, lane = tid & 63;
    const int quad = lane >> 4, l16 = lane & 15;
    const int wm = (wave & 1) * 32, wn = (wave >> 1) * 64;
    const int row0 = by * 64, col0 = bx * 128;
    const int lr = lane >> 2, lc = (lane & 3) * 8;

    f32x4 acc[2][4];
#pragma unroll
    for (int i = 0; i < 2; i++)
#pragma unroll
        for (int j = 0; j < 4; j++) acc[i][j] = 0;

    for (int k0 = 0; k0 < D_; k0 += 32) {
        __syncthreads();
        gl2lds16(&Ab[(size_t)(row0 + wave * 16 + lr) * D_ + k0 + lc],
                 &Ast[wave * 16][0]);
#pragma unroll
        for (int c = 0; c < 2; c++) {
            int m = (wave * 2 + c) * 16;
            gl2lds16(&Bt[(size_t)(col0 + m + lr) * D_ + k0 + lc], &Bst[m][0]);
        }
        __syncthreads();

        bf16x8 af[2], bfr[4];
#pragma unroll
        for (int mt = 0; mt < 2; mt++)
            af[mt] = *(const bf16x8*)&Ast[wm + mt * 16 + l16][quad * 8];
#pragma unroll
        for (int nt = 0; nt < 4; nt++)
            bfr[nt] = *(const bf16x8*)&Bst[wn + nt * 16 + l16][quad * 8];
#pragma unroll
        for (int mt = 0; mt < 2; mt++)
#pragma unroll
            for (int nt = 0; nt < 4; nt++)
                acc[mt][nt] = __builtin_amdgcn_mfma_f32_16x16x32_bf16(
                    af[mt], bfr[nt], acc[mt][nt], 0, 0, 0);
    }

#pragma unroll
    for (int mt = 0; mt < 2; mt++)
#pragma unroll
        for (int nt = 0; nt < 4; nt++)
#pragma unroll
            for (int reg = 0; reg < 4; reg++) {
                int row = row0 + wm + mt * 16 + quad * 4 + reg;
                int col = col0 + wn + nt * 16 + l16;
                out[(size_t)row * D_ + col] = acc[mt][nt][reg];
            }
}

// ---------------------------------------------------------------------------
// MFMA flash attention, round-7 structure (q-tile 128, K-chunk 128, 2 subs
// per wave) + explicit K/V DOUBLE BUFFER: chunk kt+1's async global->LDS
// loads are issued right after the barrier, so the next barrier's vmcnt
// drain finds them already landed. One barrier per kt (was two).
// LDS 77 KB -> still 2 blocks/CU. XCD swizzle: bid%8 == bh%8.
// ---------------------------------------------------------------------------
__global__ __launch_bounds__(256) void attn_mfma(
    const unsigned short* __restrict__ Qb, const unsigned short* __restrict__ Kb,
    const unsigned short* __restrict__ Vtb, const float* __restrict__ rel_emb,
    unsigned short* __restrict__ CTXb)
{
    __shared__ __align__(16) unsigned short Ks[2][2][128][32];  // [buf][d-half][kc][d32]
    __shared__ __align__(16) unsigned short Vts[2][4][64][32];  // [buf][kc-q][d][kc32]
    __shared__ __align__(16) unsigned short Pw[4][16][40];      // [wave][q][kc32 pad40]
    __shared__ float bias_tab[2047];

    const int bid = blockIdx.x;
    const int bh = bid & 63;          // (b,h): XCD residue = bh%8
    const int b = bh >> 4, h = bh & 15;
    const int q0 = (bid >> 6) * 128;
    const int tid = threadIdx.x;
    const int wave = tid >> 6, lane = tid & 63;
    const int quad = lane >> 4, l16 = lane & 15;
    const int qw = q0 + wave * 32;

    for (int idx = tid; idx < 2047; idx += 256) {
        int rel = idx - 1023;  // k - q
        int n = -rel, ret = 0;
        if (n < 0) { ret = 16; n = -n; }
        int bkt;
        if (n < 8) bkt = ret + n;
        else {
            float t = logf((float)n / 8.0f) / logf(16.0f) * 8.0f;
            int v = 8 + (int)t;
            if (v > 15) v = 15;
            bkt = ret + v;
        }
        bias_tab[idx] = rel_emb[bkt * H_ + h] * LOG2E - BIAS_OFF;
    }

    const size_t hb = (size_t)(b * H_ + h) * (S_ * DK_);
    const unsigned short* Qp = Qb + hb;
    const unsigned short* Kp = Kb + hb;
    const unsigned short* Vp = Vtb + hb;

    bf16x8 qf[2][2];
#pragma unroll
    for (int sub = 0; sub < 2; sub++)
#pragma unroll
        for (int ks = 0; ks < 2; ks++)
            qf[sub][ks] = *(const bf16x8*)
                &Qp[(size_t)(qw + sub * 16 + l16) * DK_ + ks * 32 + quad * 8];

    f32x4 O[2][4];
#pragma unroll
    for (int sub = 0; sub < 2; sub++)
#pragma unroll
        for (int dt = 0; dt < 4; dt++) O[sub][dt] = 0;
    float lsum[2][4] = {{0.f, 0.f, 0.f, 0.f}, {0.f, 0.f, 0.f, 0.f}};

    const int lr = lane >> 2, lc8 = (lane & 3) * 8;
    const int pcol = (l16 & 1) ? (8 + (l16 >> 1)) : (l16 >> 1);
    unsigned* pwp = (unsigned*)&Pw[wave][0][0];   // row stride = 20 dwords

    // async-stage one 128-wide K/V chunk into buffer db
    auto stageKV = [&](int db, int k0) {
#pragma unroll
        for (int i = 0; i < 4; i++) {
            int idx = wave * 4 + i;
            {
                int s = idx >> 3, rg = idx & 7;
                gl2lds16(&Kp[(size_t)(k0 + rg * 16 + lr) * DK_ + s * 32 + lc8],
                         &Ks[db][s][rg * 16][0]);
            }
            {
                int qt = idx >> 2, rg = idx & 3;
                gl2lds16(&Vp[(size_t)(rg * 16 + lr) * S_ + k0 + qt * 32 + lc8],
                         &Vts[db][qt][rg * 16][0]);
            }
        }
    };

    stageKV(0, 0);   // prologue: issue chunk 0

    for (int kt = 0; kt < 8; kt++) {
        const int k0 = kt * 128;
        const int db = kt & 1;
        // single barrier: drains current buffer's loads (issued one full
        // compute phase ago for kt>0) and orders the buf^1 reuse.
        __syncthreads();
        if (kt < 7) stageKV(db ^ 1, k0 + 128);   // prefetch next chunk

#pragma unroll
        for (int nt2 = 0; nt2 < 4; nt2++) {
            bf16x8 kf[2][2], vf[4];
#pragma unroll
            for (int t = 0; t < 2; t++)
#pragma unroll
                for (int ks = 0; ks < 2; ks++)
                    kf[t][ks] = *(const bf16x8*)
                        &Ks[db][ks][(2 * nt2 + t) * 16 + l16][quad * 8];
#pragma unroll
            for (int dt = 0; dt < 4; dt++)
                vf[dt] = *(const bf16x8*)&Vts[db][nt2][dt * 16 + l16][quad * 8];

#pragma unroll
            for (int sub = 0; sub < 2; sub++) {
                const int sb = qw + sub * 16;
                f32x4 sacc[2];
#pragma unroll
                for (int t = 0; t < 2; t++) {
                    int b0 = 1023 + k0 + (2 * nt2 + t) * 16 + l16 - (sb + quad * 4 + 3);
                    float bl[4];
#pragma unroll
                    for (int j = 0; j < 4; j++) bl[j] = bias_tab[b0 + j];
#pragma unroll
                    for (int reg = 0; reg < 4; reg++) sacc[t][reg] = bl[3 - reg];
                }
#pragma unroll
                for (int ks = 0; ks < 2; ks++)
#pragma unroll
                    for (int t = 0; t < 2; t++)
                        sacc[t] = __builtin_amdgcn_mfma_f32_16x16x32_bf16(
                            qf[sub][ks], kf[t][ks], sacc[t], 0, 0, 0);

#pragma unroll
                for (int reg = 0; reg < 4; reg++) {
                    float pa = exp2_fast(sacc[0][reg]);
                    float pb = exp2_fast(sacc[1][reg]);
                    lsum[sub][reg] += pa + pb;
                    float pax = dpp_xor1(pa), pbx = dpp_xor1(pb);
                    unsigned ue = pack_bf16(pa, pax);
                    unsigned uo = pack_bf16(pbx, pb);
                    pwp[(quad * 4 + reg) * 20 + pcol] = (l16 & 1) ? uo : ue;
                }

                bf16x8 pf = *(const bf16x8*)&Pw[wave][l16][quad * 8];
#pragma unroll
                for (int dt = 0; dt < 4; dt++)
                    O[sub][dt] = __builtin_amdgcn_mfma_f32_16x16x32_bf16(
                        pf, vf[dt], O[sub][dt], 0, 0, 0);
            }
        }
    }

#pragma unroll
    for (int sub = 0; sub < 2; sub++)
#pragma unroll
        for (int reg = 0; reg < 4; reg++) {
            float l = lsum[sub][reg];
#pragma unroll
            for (int off = 1; off < 16; off <<= 1)
                l += __shfl_xor(l, off);
            float inv = 1.0f / l;
            int s = qw + sub * 16 + quad * 4 + reg;
#pragma unroll
            for (int dt = 0; dt < 4; dt++) {
                int col = h * DK_ + dt * 16 + l16;
                CTXb[((size_t)(b * S_ + s)) * D_ + col] = f2bf(O[sub][dt][reg] * inv);
            }
        }
}

// ---------------------------------------------------------------------------
extern "C" void kernel_launch(void* const* d_in, const int* in_sizes, int n_in,
                              void* d_out, int out_size, void* d_ws, size_t ws_size,
                              hipStream_t stream) {
    const float* x   = (const float*)d_in[0];
    const float* Wq  = (const float*)d_in[1];
    const float* Wk  = (const float*)d_in[2];
    const float* Wv  = (const float*)d_in[3];
    const float* Wo  = (const float*)d_in[4];
    const float* rel = (const float*)d_in[5];
    float* out = (float*)d_out;

    unsigned short* ws = (unsigned short*)d_ws;
    unsigned short* xb   = ws;                       // 4194304
    unsigned short* Wts  = ws + (size_t)4194304;     // 4x1048576
    unsigned short* Qb   = ws + (size_t)8388608;
    unsigned short* Kb   = ws + (size_t)12582912;
    unsigned short* Vtb  = ws + (size_t)16777216;
    unsigned short* CTXb = ws + (size_t)20971520;

    conv_all<<<8192, 256, 0, stream>>>(x, Wq, Wk, Wv, Wo, xb, Wts);
    gemm_qkv<<<768, 256, 0, stream>>>(xb, Wts, Qb, Kb, Vtb);
    attn_mfma<<<512, 256, 0, stream>>>(Qb, Kb, Vtb, rel, CTXb);
    gemm_out<<<512, 256, 0, stream>>>(CTXb, Wts + (size_t)3 * 1048576, out);
}